// Round 13
// baseline (253.906 us; speedup 1.0000x reference)
//
#include <hip/hip_runtime.h>
#include <hip/hip_bf16.h>
#include <math.h>

#define Ddim 1024
#define Mrows 4096
#define Ncols 8192
#define BM 128
#define BN 128
#define BK 32
#define NCS 64                         // 64 col-split blocks of 128 cols
#define CS 64                          // lse partials per row (128 cols each)
#define RT (Mrows / BM)                // 32
#define KITERS (Ddim / BK)             // 32
#define SCALE 20.0f                    // 1/TEMPERATURE
#define ARR_ELEMS (Mrows * Ddim)       // 4194304 per input array

typedef __bf16 bf16_t;
typedef __bf16 bf16x8 __attribute__((ext_vector_type(8)));
typedef float f32x4 __attribute__((ext_vector_type(4)));

// global->LDS DMA, 16B per lane, lds dest = wave-uniform base + lane*16
#define LOAD16_TO_LDS(g, l)                                                  \
  __builtin_amdgcn_global_load_lds(                                          \
      (const __attribute__((address_space(1))) void*)(g),                    \
      (__attribute__((address_space(3))) void*)(l), 16, 0, 0)

// ---------------------------------------------------------------------------
// Kernel 0: f32 -> bf16 conversion pre-pass; thread (0,0) also zeroes the
// output scalar (stream order guarantees it lands before hungarian's atomics).
// ---------------------------------------------------------------------------
__global__ __launch_bounds__(256) void cvt_kernel(
    const float* __restrict__ o, const float* __restrict__ pos,
    const float* __restrict__ neg, bf16_t* __restrict__ ob,
    bf16_t* __restrict__ pb, bf16_t* __restrict__ nb,
    float* __restrict__ out)
{
  if (blockIdx.x == 0 && threadIdx.x == 0) out[0] = 0.f;
  const int idx = blockIdx.x * 256 + threadIdx.x;   // 0 .. 3*ARR/8-1
  const int seg = idx >> 19;                        // ARR_ELEMS/8 = 2^19
  const int off = idx & ((1 << 19) - 1);
  const float* src = (seg == 0) ? o : (seg == 1) ? pos : neg;
  bf16_t* dst = (seg == 0) ? ob : (seg == 1) ? pb : nb;
  const float4 v0 = *(const float4*)(src + (size_t)off * 8);
  const float4 v1 = *(const float4*)(src + (size_t)off * 8 + 4);
  bf16x8 r = {(bf16_t)v0.x, (bf16_t)v0.y, (bf16_t)v0.z, (bf16_t)v0.w,
              (bf16_t)v1.x, (bf16_t)v1.y, (bf16_t)v1.z, (bf16_t)v1.w};
  *(bf16x8*)(dst + (size_t)off * 8) = r;
}

// ---------------------------------------------------------------------------
// Kernel 1: bf16 GEMM (o · emb^T) + partial LSE + diagonal-block extraction.
// R12 configuration (best measured gemm: 87.5 us): 128x128 block, 4 waves of
// 32x128 stripes, 64-AGPR acc, 4 waves/SIMD, double-buffered LDS +
// global_load_lds DMA + XOR source-swizzle (0 conflicts). UNCHANGED.
// ---------------------------------------------------------------------------
__global__ __launch_bounds__(256, 4) void gemm_lse_kernel(
    const bf16_t* __restrict__ ob, const bf16_t* __restrict__ pb,
    const bf16_t* __restrict__ nb, float* __restrict__ pm,
    float* __restrict__ pl, float* __restrict__ blocks_raw)
{
  __shared__ bf16_t As[2][BM * BK];   // 2 x 8 KB
  __shared__ bf16_t Bs[2][BN * BK];   // 2 x 8 KB

  const int bid = blockIdx.x;
  const int rt = bid >> 6;        // 0..31
  const int cs = bid & 63;        // 0..63
  const int row0 = rt * BM;
  const bf16_t* Eb = (cs < 32) ? (pb + (size_t)cs * BN * Ddim)
                               : (nb + (size_t)(cs - 32) * BN * Ddim);

  const int t = threadIdx.x;
  const int wave = t >> 6;
  const int lane = t & 63;
  const int quad = lane >> 4;
  const int l16 = lane & 15;
  const int koff = ((quad ^ ((l16 >> 1) & 3)) << 3);   // fragment chunk offset
  const int lr4 = lane >> 2;                            // staging row-in-16
  const int cstg = lane & 3;                            // staging chunk id

  f32x4 acc[2][8];
#pragma unroll
  for (int a = 0; a < 2; ++a)
#pragma unroll
    for (int b = 0; b < 8; ++b) acc[a][b] = (f32x4){0.f, 0.f, 0.f, 0.f};

  // prologue: stage tile 0 into buffer 0 (each wave stages 32 rows of A & B)
#pragma unroll
  for (int cl = 0; cl < 2; ++cl) {
    const int r = wave * 32 + cl * 16 + lr4;
    const int gc = cstg ^ ((r >> 1) & 3);
    LOAD16_TO_LDS(ob + (size_t)(row0 + r) * Ddim + gc * 8,
                  &As[0][(wave * 32 + cl * 16) * BK]);
    LOAD16_TO_LDS(Eb + (size_t)r * Ddim + gc * 8,
                  &Bs[0][(wave * 32 + cl * 16) * BK]);
  }

  int p = 0;
  for (int kc = 0; kc < KITERS; ++kc) {
    __syncthreads();   // drains DMA for buf p; protects buf p^1 reuse
    if (kc + 1 < KITERS) {
      const int k0 = (kc + 1) * BK;
#pragma unroll
      for (int cl = 0; cl < 2; ++cl) {
        const int r = wave * 32 + cl * 16 + lr4;
        const int gc = cstg ^ ((r >> 1) & 3);
        LOAD16_TO_LDS(ob + (size_t)(row0 + r) * Ddim + k0 + gc * 8,
                      &As[p ^ 1][(wave * 32 + cl * 16) * BK]);
        LOAD16_TO_LDS(Eb + (size_t)r * Ddim + k0 + gc * 8,
                      &Bs[p ^ 1][(wave * 32 + cl * 16) * BK]);
      }
    }

    const int rowA0 = wave * 32 + l16;
    const bf16x8 a0 = *(const bf16x8*)(&As[p][rowA0 * BK + koff]);
    const bf16x8 a1 = *(const bf16x8*)(&As[p][(rowA0 + 16) * BK + koff]);
#pragma unroll
    for (int fn = 0; fn < 8; ++fn) {
      const bf16x8 bf = *(const bf16x8*)(&Bs[p][(fn * 16 + l16) * BK + koff]);
      acc[0][fn] = __builtin_amdgcn_mfma_f32_16x16x32_bf16(a0, bf, acc[0][fn], 0, 0, 0);
      acc[1][fn] = __builtin_amdgcn_mfma_f32_16x16x32_bf16(a1, bf, acc[1][fn], 0, 0, 0);
    }
    p ^= 1;
  }

  // epilogue A: per-row (m, l) over this block's 128 cols.
#pragma unroll
  for (int fm = 0; fm < 2; ++fm) {
#pragma unroll
    for (int r = 0; r < 4; ++r) {
      float s[8];
#pragma unroll
      for (int fn = 0; fn < 8; ++fn) s[fn] = acc[fm][fn][r] * SCALE;
      float m = s[0];
#pragma unroll
      for (int fn = 1; fn < 8; ++fn) m = fmaxf(m, s[fn]);
#pragma unroll
      for (int off = 1; off <= 8; off <<= 1)
        m = fmaxf(m, __shfl_xor(m, off, 64));   // row max over l16 group
      float l = 0.f;
#pragma unroll
      for (int fn = 0; fn < 8; ++fn) l += __expf(s[fn] - m);
#pragma unroll
      for (int off = 1; off <= 8; off <<= 1)
        l += __shfl_xor(l, off, 64);
      if (l16 == 0) {
        const int rg = row0 + wave * 32 + fm * 16 + quad * 4 + r;
        pm[(size_t)rg * CS + cs] = m;
        pl[(size_t)rg * CS + cs] = l;
      }
    }
  }

  // epilogue B: diagonal 16x16 sub-blocks via guarded constant-index unroll.
  if (cs == rt) {
#pragma unroll
    for (int fm = 0; fm < 2; ++fm) {
      const int d = 2 * wave + fm;         // runtime, but acc idx below const
      const int b = rt * 8 + d;
#pragma unroll
      for (int fn = 0; fn < 8; ++fn) {
        if (fn == d) {
#pragma unroll
          for (int r = 0; r < 4; ++r)
            blocks_raw[b * 256 + (quad * 4 + r) * 16 + l16] = acc[fm][fn][r] * SCALE;
        }
      }
    }
  }
}

// select c[k], k in 0..15, from a constant-indexed register array via a
// 15-op cndmask tree (no dynamic register indexing -> no scratch demotion)
__device__ __forceinline__ float select16(const float c[16], int k) {
  float t8[8], t4[4], t2[2];
#pragma unroll
  for (int i = 0; i < 8; ++i) t8[i] = (k & 1) ? c[2 * i + 1] : c[2 * i];
#pragma unroll
  for (int i = 0; i < 4; ++i) t4[i] = (k & 2) ? t8[2 * i + 1] : t8[2 * i];
#pragma unroll
  for (int i = 0; i < 2; ++i) t2[i] = (k & 4) ? t4[2 * i + 1] : t4[2 * i];
  return (k & 8) ? t2[1] : t2[0];
}

// full-wave64 min via DPP (row_shr 1/2/4/8 + row_bcast 15/31), ~50 cyc vs
// ~200 for a 5-stage shfl_xor butterfly. old = x so invalid lanes are no-ops.
__device__ __forceinline__ float wave_min64(float x) {
#define DPP_STEP(ctrl)                                                        \
  {                                                                           \
    int xi = __builtin_bit_cast(int, x);                                      \
    int yi = __builtin_amdgcn_update_dpp(xi, xi, ctrl, 0xf, 0xf, false);      \
    x = fminf(x, __builtin_bit_cast(float, yi));                              \
  }
  DPP_STEP(0x111)  // row_shr:1
  DPP_STEP(0x112)  // row_shr:2
  DPP_STEP(0x114)  // row_shr:4
  DPP_STEP(0x118)  // row_shr:8
  DPP_STEP(0x142)  // row_bcast:15
  DPP_STEP(0x143)  // row_bcast:31
#undef DPP_STEP
  return __builtin_bit_cast(
      float, __builtin_amdgcn_readlane(__builtin_bit_cast(int, x), 63));
}

// ---------------------------------------------------------------------------
// Kernel 2: fused lse-combine + lane-parallel JV LAP + atomic loss. v4:
// - w[16] = -C[i][col] - u[i] register-resident per lane; u updates folded in
//   via uniform tree bitmask (w[i] -= delta for tree rows) -> the per-step
//   shfl(u) + 120-cyc LDS C read collapse to one ~35-cyc select16.
// - DPP wave-min + ballot/ctz argmin (tiebreak-free: any optimal assignment
//   gives the identical loss, since sum(lse) is assignment-independent).
// - readlane (uniform index) for all broadcasts.
// Single wave per block, no barriers.
// ---------------------------------------------------------------------------
__global__ __launch_bounds__(64) void hungarian_kernel(
    const float* __restrict__ blocks_raw, const float* __restrict__ pm,
    const float* __restrict__ pl, float* __restrict__ out)
{
  const int b = blockIdx.x;
  const int L = threadIdx.x;
  __shared__ float lse_s[16];

  // lane j (1..16) holds column j-1 of C: c[i] = C[i][j-1]; w = -c - u (u=0)
  const int jc = (L >= 1 && L <= 16) ? (L - 1) : 0;
  float c[16], w[16];
#pragma unroll
  for (int i = 0; i < 16; ++i) {
    c[i] = blocks_raw[b * 256 + i * 16 + jc];
    w[i] = -c[i];
  }

  // combine 64 partial (m,l) per row -> lse_s. lane = r + 16*g handles
  // partial chunk [g*16, g*16+16) of row r, then merges across g.
  {
    const int r = L & 15, g = L >> 4;
    const size_t base = (size_t)(b * 16 + r) * CS + g * 16;
    float m = -INFINITY, l = 0.f;
#pragma unroll
    for (int k = 0; k < 16; ++k) {
      const float m2 = pm[base + k];
      const float l2 = pl[base + k];
      const float M = fmaxf(m, m2);
      l = l * __expf(m - M) + l2 * __expf(m2 - M);
      m = M;
    }
#pragma unroll
    for (int off = 16; off <= 32; off <<= 1) {
      const float m2 = __shfl_xor(m, off, 64);
      const float l2 = __shfl_xor(l, off, 64);
      const float M = fmaxf(m, m2);
      l = l * __expf(m - M) + l2 * __expf(m2 - M);
      m = M;
    }
    if (g == 0) lse_s[r] = m + logf(l);
  }

  const float INF = 3.0e38f;
  float vj = 0.f;
  int pj = 0;                    // p[L]: row matched to column L (0 = none)
  float minv = INF;
  int wayj = 0;
  bool usedj = false;

  for (int i = 1; i <= 16; ++i) {
    if (L == 0) pj = i;          // p[0] = current row (read during augment)
    minv = INF; wayj = 0; usedj = false;
    unsigned tree = 0;           // uniform bitmask of rows in this phase tree
    int j0 = 0;
    int i0 = i;                  // row entering the tree (uniform)
    while (true) {
      usedj = usedj || (L == j0);
      tree |= 1u << (i0 - 1);
      const float wi0 = select16(w, i0 - 1);      // -C[i0-1][L-1] - u[i0]
      if (L >= 1 && L <= 16 && !usedj) {
        const float cur = wi0 - vj;
        if (cur < minv) { minv = cur; wayj = j0; }
      }
      const float cand = (L >= 1 && L <= 16 && !usedj) ? minv : INF;
      const float delta = wave_min64(cand);
      const unsigned long long bal = __ballot(cand == delta);
      const int j1 = (int)__builtin_ctzll(bal);
      if (L >= 1 && L <= 16) {
        if (usedj) vj -= delta; else minv -= delta;
      }
      // u[i] += delta for tree rows  <=>  w[i] -= delta (uniform predicate)
#pragma unroll
      for (int k = 0; k < 16; ++k)
        if (tree & (1u << k)) w[k] -= delta;
      j0 = j1;
      i0 = __builtin_amdgcn_readlane(pj, j0);
      if (i0 == 0) break;        // reached an unmatched column
    }
    // augment along way[] path
    while (j0 != 0) {
      const int j1a = __builtin_amdgcn_readlane(wayj, j0);
      const int pjn = __builtin_amdgcn_readlane(pj, j1a);
      if (L == j0) pj = pjn;
      j0 = j1a;
    }
  }

  float loss = 0.f;
  if (L >= 1 && L <= 16) loss = lse_s[pj - 1] - select16(c, pj - 1);
#pragma unroll
  for (int off = 32; off > 0; off >>= 1) loss += __shfl_down(loss, off, 64);
  if (L == 0) atomicAdd(out, loss * (1.0f / 4096.0f));
}

extern "C" void kernel_launch(void* const* d_in, const int* in_sizes, int n_in,
                              void* d_out, int out_size, void* d_ws, size_t ws_size,
                              hipStream_t stream) {
  const float* o   = (const float*)d_in[0];  // (256,16,1024) f32
  const float* pos = (const float*)d_in[1];
  const float* neg = (const float*)d_in[2];
  float* out = (float*)d_out;

  float* ws = (float*)d_ws;
  float* pm         = ws;                       // 4096*64 = 1 MB
  float* pl         = pm + (size_t)4096 * CS;   // 4096*64 = 1 MB
  float* blocks_raw = pl + (size_t)4096 * CS;   // 256*256
  bf16_t* ob = (bf16_t*)(blocks_raw + 65536);   // 3 x 4194304 bf16
  bf16_t* pb = ob + (size_t)ARR_ELEMS;
  bf16_t* nb = pb + (size_t)ARR_ELEMS;

  cvt_kernel<<<3 * ARR_ELEMS / 8 / 256, 256, 0, stream>>>(o, pos, neg, ob, pb, nb, out);
  gemm_lse_kernel<<<RT * NCS, 256, 0, stream>>>(ob, pb, nb, pm, pl, blocks_raw);
  hungarian_kernel<<<256, 64, 0, stream>>>(blocks_raw, pm, pl, out);
}

// Round 14
// 218.765 us; speedup vs baseline: 1.1606x; 1.1606x over previous
//
#include <hip/hip_runtime.h>
#include <hip/hip_bf16.h>
#include <math.h>

#define Ddim 1024
#define Mrows 4096
#define Ncols 8192
#define BM 128
#define BN 128
#define BK 32
#define NCS 64                         // 64 col-split blocks of 128 cols
#define CS 64                          // lse partials per row (128 cols each)
#define RT (Mrows / BM)                // 32
#define KITERS (Ddim / BK)             // 32
#define NSOLVE 256                     // hungarian solve blocks (dispatch 1st)
#define SCALE 20.0f                    // 1/TEMPERATURE
#define ARR_ELEMS (Mrows * Ddim)       // 4194304 per input array

typedef __bf16 bf16_t;
typedef __bf16 bf16x8 __attribute__((ext_vector_type(8)));
typedef float f32x4 __attribute__((ext_vector_type(4)));

// global->LDS DMA, 16B per lane, lds dest = wave-uniform base + lane*16
#define LOAD16_TO_LDS(g, l)                                                  \
  __builtin_amdgcn_global_load_lds(                                          \
      (const __attribute__((address_space(1))) void*)(g),                    \
      (__attribute__((address_space(3))) void*)(l), 16, 0, 0)

// ---------------------------------------------------------------------------
// Kernel 0: f32 -> bf16 conversion pre-pass; thread (0,0) zeroes the output.
// ---------------------------------------------------------------------------
__global__ __launch_bounds__(256) void cvt_kernel(
    const float* __restrict__ o, const float* __restrict__ pos,
    const float* __restrict__ neg, bf16_t* __restrict__ ob,
    bf16_t* __restrict__ pb, bf16_t* __restrict__ nb,
    float* __restrict__ out)
{
  if (blockIdx.x == 0 && threadIdx.x == 0) out[0] = 0.f;
  const int idx = blockIdx.x * 256 + threadIdx.x;   // 0 .. 3*ARR/8-1
  const int seg = idx >> 19;                        // ARR_ELEMS/8 = 2^19
  const int off = idx & ((1 << 19) - 1);
  const float* src = (seg == 0) ? o : (seg == 1) ? pos : neg;
  bf16_t* dst = (seg == 0) ? ob : (seg == 1) ? pb : nb;
  const float4 v0 = *(const float4*)(src + (size_t)off * 8);
  const float4 v1 = *(const float4*)(src + (size_t)off * 8 + 4);
  bf16x8 r = {(bf16_t)v0.x, (bf16_t)v0.y, (bf16_t)v0.z, (bf16_t)v0.w,
              (bf16_t)v1.x, (bf16_t)v1.y, (bf16_t)v1.z, (bf16_t)v1.w};
  *(bf16x8*)(dst + (size_t)off * 8) = r;
}

// ---------------------------------------------------------------------------
// Kernel 1: exact fp32 diagonal 16x16 blocks (R2-proven). Feeds the solve.
// ---------------------------------------------------------------------------
__global__ __launch_bounds__(256) void block_dots_kernel(
    const float* __restrict__ o, const float* __restrict__ pos,
    float* __restrict__ blocks_raw)
{
  const int b = blockIdx.x;
  const int i = threadIdx.x >> 4;
  const int j = threadIdx.x & 15;
  const float* orow = o + (size_t)(b * 16 + i) * Ddim;
  const float* prow = pos + (size_t)(b * 16 + j) * Ddim;
  float s0 = 0.f, s1 = 0.f, s2 = 0.f, s3 = 0.f;
  for (int k = 0; k < Ddim; k += 4) {
    const float4 a = *(const float4*)(orow + k);
    const float4 e = *(const float4*)(prow + k);
    s0 = fmaf(a.x, e.x, s0); s1 = fmaf(a.y, e.y, s1);
    s2 = fmaf(a.z, e.z, s2); s3 = fmaf(a.w, e.w, s3);
  }
  blocks_raw[b * 256 + threadIdx.x] = (s0 + s1 + s2 + s3) * SCALE;
}

// ---------------------------------------------------------------------------
// Kernel 2 (MEGA): blocks 0..255 = lane-parallel JV solve (R7-v2, 1 wave,
// latency-bound, near-zero pipe usage); blocks 256..2303 = R12's bf16 GEMM +
// partial-LSE. Solve blocks dispatch FIRST so their ~100 us dependent chain
// runs concurrently with (and hides under) the GEMM's ~90 us of real work.
// Key identity: sum_matched lse == sum_all_rows lse (p is a permutation per
// block), so the solve only contributes -sum(C_matched)/4096; the lse term
// attaches in lse_sum_kernel afterwards. Branch is block-uniform; solve path
// has no barriers (threads 64..255 exit).
// ---------------------------------------------------------------------------
__global__ __launch_bounds__(256, 4) void mega_kernel(
    const bf16_t* __restrict__ ob, const bf16_t* __restrict__ pb,
    const bf16_t* __restrict__ nb, const float* __restrict__ blocks_raw,
    float* __restrict__ pm, float* __restrict__ pl, float* __restrict__ out)
{
  __shared__ bf16_t As[2][BM * BK];   // 2 x 8 KB (gemm path)
  __shared__ bf16_t Bs[2][BN * BK];   // 2 x 8 KB
  __shared__ float Csolve[16][16];    // 1 KB (solve path)

  if (blockIdx.x < NSOLVE) {
    // ---------------- Hungarian solve path (v2, best measured) ------------
    if (threadIdx.x >= 64) return;
    const int b = blockIdx.x;
    const int L = threadIdx.x;
    for (int e = L; e < 256; e += 64)
      Csolve[e >> 4][e & 15] = blocks_raw[b * 256 + e];
    // single wave, wave-ordered LDS: no barrier needed

    const float INF = 3.0e38f;
    float vj = 0.f, u_reg = 0.f;
    int pj = 0;
    float minv = INF;
    int wayj = 0;
    bool usedj = false, on_tree = false;

    for (int i = 1; i <= 16; ++i) {
      if (L == 0) pj = i;
      minv = INF; wayj = 0; usedj = false; on_tree = false;
      int j0 = 0;
      while (true) {
        usedj = usedj || (L == j0);
        const int i0 = __shfl(pj, j0, 64);
        if (L == i0) on_tree = true;
        const float ui0 = __shfl(u_reg, i0, 64);
        if (L >= 1 && L <= 16 && !usedj) {
          const float cur = -Csolve[i0 - 1][L - 1] - ui0 - vj;
          if (cur < minv) { minv = cur; wayj = j0; }
        }
        float cand = (L >= 1 && L <= 16 && !usedj) ? minv : INF;
        int idx = L;
#pragma unroll
        for (int off = 16; off > 0; off >>= 1) {
          const float ov = __shfl_xor(cand, off, 32);
          const int oi = __shfl_xor(idx, off, 32);
          if (ov < cand || (ov == cand && oi < idx)) { cand = ov; idx = oi; }
        }
        const float delta = cand;                  // valid in lanes 0..31
        const int j1 = __builtin_amdgcn_readfirstlane(idx);
        if (L >= 1 && L <= 16) {
          if (usedj) vj -= delta; else minv -= delta;
          if (on_tree) u_reg += delta;
        }
        j0 = j1;
        const int pj0 = __shfl(pj, j0, 64);
        if (pj0 == 0) break;
      }
      while (j0 != 0) {
        const int j1a = __shfl(wayj, j0, 64);
        const int pjn = __shfl(pj, j1a, 64);
        if (L == j0) pj = pjn;
        j0 = j1a;
      }
    }

    float loss = 0.f;
    if (L >= 1 && L <= 16) loss = -Csolve[pj - 1][L - 1];
#pragma unroll
    for (int off = 32; off > 0; off >>= 1) loss += __shfl_down(loss, off, 64);
    if (L == 0) atomicAdd(out, loss * (1.0f / 4096.0f));
    return;
  }

  // ------------------------- GEMM + partial-LSE path ----------------------
  const int bid = blockIdx.x - NSOLVE;
  const int rt = bid >> 6;        // 0..31
  const int cs = bid & 63;        // 0..63
  const int row0 = rt * BM;
  const bf16_t* Eb = (cs < 32) ? (pb + (size_t)cs * BN * Ddim)
                               : (nb + (size_t)(cs - 32) * BN * Ddim);

  const int t = threadIdx.x;
  const int wave = t >> 6;
  const int lane = t & 63;
  const int quad = lane >> 4;
  const int l16 = lane & 15;
  const int koff = ((quad ^ ((l16 >> 1) & 3)) << 3);   // fragment chunk offset
  const int lr4 = lane >> 2;                            // staging row-in-16
  const int cstg = lane & 3;                            // staging chunk id

  f32x4 acc[2][8];
#pragma unroll
  for (int a = 0; a < 2; ++a)
#pragma unroll
    for (int b2 = 0; b2 < 8; ++b2) acc[a][b2] = (f32x4){0.f, 0.f, 0.f, 0.f};

  // prologue: stage tile 0 into buffer 0 (each wave stages 32 rows of A & B)
#pragma unroll
  for (int cl = 0; cl < 2; ++cl) {
    const int r = wave * 32 + cl * 16 + lr4;
    const int gc = cstg ^ ((r >> 1) & 3);
    LOAD16_TO_LDS(ob + (size_t)(row0 + r) * Ddim + gc * 8,
                  &As[0][(wave * 32 + cl * 16) * BK]);
    LOAD16_TO_LDS(Eb + (size_t)r * Ddim + gc * 8,
                  &Bs[0][(wave * 32 + cl * 16) * BK]);
  }

  int p = 0;
  for (int kc = 0; kc < KITERS; ++kc) {
    __syncthreads();   // drains DMA for buf p; protects buf p^1 reuse
    if (kc + 1 < KITERS) {
      const int k0 = (kc + 1) * BK;
#pragma unroll
      for (int cl = 0; cl < 2; ++cl) {
        const int r = wave * 32 + cl * 16 + lr4;
        const int gc = cstg ^ ((r >> 1) & 3);
        LOAD16_TO_LDS(ob + (size_t)(row0 + r) * Ddim + k0 + gc * 8,
                      &As[p ^ 1][(wave * 32 + cl * 16) * BK]);
        LOAD16_TO_LDS(Eb + (size_t)r * Ddim + k0 + gc * 8,
                      &Bs[p ^ 1][(wave * 32 + cl * 16) * BK]);
      }
    }

    const int rowA0 = wave * 32 + l16;
    const bf16x8 a0 = *(const bf16x8*)(&As[p][rowA0 * BK + koff]);
    const bf16x8 a1 = *(const bf16x8*)(&As[p][(rowA0 + 16) * BK + koff]);
#pragma unroll
    for (int fn = 0; fn < 8; ++fn) {
      const bf16x8 bf = *(const bf16x8*)(&Bs[p][(fn * 16 + l16) * BK + koff]);
      acc[0][fn] = __builtin_amdgcn_mfma_f32_16x16x32_bf16(a0, bf, acc[0][fn], 0, 0, 0);
      acc[1][fn] = __builtin_amdgcn_mfma_f32_16x16x32_bf16(a1, bf, acc[1][fn], 0, 0, 0);
    }
    p ^= 1;
  }

  // epilogue: per-row (m, l) over this block's 128 cols.
  // C/D: col = fn*16 + l16, row = wave*32 + fm*16 + quad*4 + r
#pragma unroll
  for (int fm = 0; fm < 2; ++fm) {
#pragma unroll
    for (int r = 0; r < 4; ++r) {
      float s[8];
#pragma unroll
      for (int fn = 0; fn < 8; ++fn) s[fn] = acc[fm][fn][r] * SCALE;
      float m = s[0];
#pragma unroll
      for (int fn = 1; fn < 8; ++fn) m = fmaxf(m, s[fn]);
#pragma unroll
      for (int off = 1; off <= 8; off <<= 1)
        m = fmaxf(m, __shfl_xor(m, off, 64));   // row max over l16 group
      float l = 0.f;
#pragma unroll
      for (int fn = 0; fn < 8; ++fn) l += __expf(s[fn] - m);
#pragma unroll
      for (int off = 1; off <= 8; off <<= 1)
        l += __shfl_xor(l, off, 64);
      if (l16 == 0) {
        const int rg = row0 + wave * 32 + fm * 16 + quad * 4 + r;
        pm[(size_t)rg * CS + cs] = m;
        pl[(size_t)rg * CS + cs] = l;
      }
    }
  }
}

// ---------------------------------------------------------------------------
// Kernel 3: per-row lse from partials, then atomicAdd sum(lse)/4096.
// ---------------------------------------------------------------------------
__global__ __launch_bounds__(256) void lse_sum_kernel(
    const float* __restrict__ pm, const float* __restrict__ pl,
    float* __restrict__ out)
{
  const int r = blockIdx.x * 256 + threadIdx.x;   // 0..4095
  const size_t base = (size_t)r * CS;
  float m = -INFINITY, l = 0.f;
#pragma unroll
  for (int k = 0; k < CS; ++k) {
    const float m2 = pm[base + k];
    const float l2 = pl[base + k];
    const float M = fmaxf(m, m2);
    l = l * __expf(m - M) + l2 * __expf(m2 - M);
    m = M;
  }
  float v = m + logf(l);
#pragma unroll
  for (int off = 32; off > 0; off >>= 1) v += __shfl_down(v, off, 64);
  __shared__ float wsum[4];
  if ((threadIdx.x & 63) == 0) wsum[threadIdx.x >> 6] = v;
  __syncthreads();
  if (threadIdx.x == 0)
    atomicAdd(out, (wsum[0] + wsum[1] + wsum[2] + wsum[3]) * (1.0f / 4096.0f));
}

extern "C" void kernel_launch(void* const* d_in, const int* in_sizes, int n_in,
                              void* d_out, int out_size, void* d_ws, size_t ws_size,
                              hipStream_t stream) {
  const float* o   = (const float*)d_in[0];  // (256,16,1024) f32
  const float* pos = (const float*)d_in[1];
  const float* neg = (const float*)d_in[2];
  float* out = (float*)d_out;

  float* ws = (float*)d_ws;
  float* pm         = ws;                       // 4096*64 = 1 MB
  float* pl         = pm + (size_t)4096 * CS;   // 4096*64 = 1 MB
  float* blocks_raw = pl + (size_t)4096 * CS;   // 256*256
  bf16_t* ob = (bf16_t*)(blocks_raw + 65536);   // 3 x 4194304 bf16
  bf16_t* pb = ob + (size_t)ARR_ELEMS;
  bf16_t* nb = pb + (size_t)ARR_ELEMS;

  cvt_kernel<<<3 * ARR_ELEMS / 8 / 256, 256, 0, stream>>>(o, pos, neg, ob, pb, nb, out);
  block_dots_kernel<<<256, 256, 0, stream>>>(o, pos, blocks_raw);
  mega_kernel<<<NSOLVE + RT * NCS, 256, 0, stream>>>(ob, pb, nb, blocks_raw, pm, pl, out);
  lse_sum_kernel<<<4096 / 256, 256, 0, stream>>>(pm, pl, out);
}